// Round 9
// baseline (1061.522 us; speedup 1.0000x reference)
//
#include <hip/hip_runtime.h>
#include <stdint.h>

#define EPS 1e-5f

typedef __attribute__((ext_vector_type(8))) short short8;
typedef __attribute__((ext_vector_type(4))) float floatx4;
typedef __attribute__((ext_vector_type(4))) unsigned uintx4;
typedef unsigned short u16;

__device__ __forceinline__ u16 f2bf(float f) {
  unsigned u = __builtin_bit_cast(unsigned, f);
  u += 0x7fffu + ((u >> 16) & 1u);
  return (u16)(u >> 16);
}
__device__ __forceinline__ float bf2f(u16 h) {
  return __builtin_bit_cast(float, (unsigned)h << 16);
}
__device__ __forceinline__ unsigned pack2bf(float a, float b) {
  return (unsigned)f2bf(a) | ((unsigned)f2bf(b) << 16);
}
__device__ __forceinline__ float silu_f(float x) { return x / (1.f + __expf(-x)); }
__device__ __forceinline__ float wave_sum(float x) {
  for (int off = 32; off > 0; off >>= 1) x += __shfl_xor(x, off);
  return x;
}

// ---------------------------------------------------------------------------
// prep: swizzle weights into MFMA fragment order + float4-packed k-major
// matrices for the head kernel.
// ---------------------------------------------------------------------------
__global__ void prep_kernel(const float* __restrict__ hp_w, const float* __restrict__ conv_w,
                            const float* __restrict__ attn_in_w,
                            const float* __restrict__ attn_out_w,
                            const float* __restrict__ tw_w, const float* __restrict__ r1_w,
                            const float* __restrict__ r2_w,
                            u16* __restrict__ w1f, u16* __restrict__ w2f,
                            float* __restrict__ woT,
                            float* __restrict__ twT, float* __restrict__ r1T,
                            float* __restrict__ r2T) {
  int t = blockIdx.x * 256 + threadIdx.x;  // 0..65535
  if (t < 32768) {
    int j = t & 7, lane = (t >> 3) & 63, ks = (t >> 9) & 3, nt = t >> 11;
    int k = ks * 32 + ((lane >> 4) << 3) + j;
    int n = nt * 16 + (lane & 15);
    float v = (n < 64) ? hp_w[n * 128 + k]
                       : conv_w[((n - 64) & 63) * 384 + k * 3 + ((n - 64) >> 6)];
    w1f[t] = f2bf(v);
  }
  if (t < 8192) {
    int j = t & 7, lane = (t >> 3) & 63, ks = (t >> 9) & 1, nt = t >> 10;
    int k = ks * 32 + ((lane >> 4) << 3) + j;
    int n = nt * 16 + (lane & 15);
    w2f[t] = f2bf(attn_in_w[(64 + n) * 64 + k]);
  }
  if (t < 4096) {
    int j = t & 63, k = t >> 6;
    woT[k * 64 + j] = attn_out_w[j * 64 + k];
  }
  if (t < 8320) {  // twT[k4 0..64][mid 0..127][4]; k=257..259 zero-padded
    int mid = t & 127, k4 = t >> 7;
#pragma unroll
    for (int i = 0; i < 4; ++i) {
      int k = k4 * 4 + i;
      twT[t * 4 + i] = (k < 257) ? tw_w[mid * 257 + k] : 0.f;
    }
  }
  if (t < 16384) {  // r1T/r2T[k4 0..63][o 0..255][4]
    int o = t & 255, k4 = t >> 8;
#pragma unroll
    for (int i = 0; i < 4; ++i) {
      r1T[t * 4 + i] = r1_w[o * 256 + k4 * 4 + i];
      r2T[t * 4 + i] = r2_w[o * 256 + k4 * 4 + i];
    }
  }
}

// ---------------------------------------------------------------------------
// team_kernel: per-team q = temb[t]@qp_w.T + qp_b ; qh = q@wq.T + bq
// ---------------------------------------------------------------------------
__global__ __launch_bounds__(64) void team_kernel(
    const float* __restrict__ temb, const float* __restrict__ qp_w,
    const float* __restrict__ qp_b, const float* __restrict__ attn_in_w,
    const float* __restrict__ attn_in_b,
    float* __restrict__ Qg, float* __restrict__ QHg) {
  __shared__ float e[96];
  __shared__ float qv[64];
  const int t = blockIdx.x;   // team id 0..399
  const int o = threadIdx.x;  // 0..63
  for (int i = o; i < 96; i += 64) e[i] = temb[t * 96 + i];
  __syncthreads();
  float acc = qp_b[o];
  for (int k = 0; k < 96; ++k) acc += e[k] * qp_w[o * 96 + k];
  qv[o] = acc;
  Qg[t * 64 + o] = acc;
  __syncthreads();
  float acc2 = attn_in_b[o];
  for (int k = 0; k < 64; ++k) acc2 += qv[k] * attn_in_w[o * 64 + k];
  QHg[t * 64 + o] = acc2;
}

// ---------------------------------------------------------------------------
// attn_kernel: round-6 structure, __launch_bounds__(256,3) occupancy push.
// Transient weight fragments; total regs (VGPR+AGPR unified) should fit the
// ~170/wave cap for 3 waves/SIMD. Diagnostic if wrong: VGPR_Count drops and
// FETCH_SIZE explodes (spill-to-scratch, r3/r4 signature) -> revert to (256,2).
// ---------------------------------------------------------------------------
__global__ __launch_bounds__(256, 3) void attn_kernel(
    const int* __restrict__ idA, const int* __restrict__ idB,
    const float* __restrict__ hnA, const float* __restrict__ hnB,
    const int* __restrict__ oppA, const int* __restrict__ oppB,
    const float* __restrict__ mskA, const float* __restrict__ mskB,
    const float* __restrict__ temb, const float* __restrict__ conv_b,
    const float* __restrict__ cbn_g, const float* __restrict__ cbn_b,
    const float* __restrict__ cbn_rm, const float* __restrict__ cbn_rv,
    const float* __restrict__ hp_b,
    const float* __restrict__ attn_in_b, const float* __restrict__ attn_out_b,
    const float* __restrict__ ln_g, const float* __restrict__ ln_b,
    const u16* __restrict__ w1f, const u16* __restrict__ w2f,
    const float* __restrict__ woT,
    const float* __restrict__ Qg, const float* __restrict__ QHg,
    float* __restrict__ ATT) {
  __shared__ __align__(16) u16 xb[48 * 136];    // x tile bf16, padded stride
  __shared__ __align__(16) u16 ybuf[48 * 264];  // Y bf16; aliased as KVP fp32
  __shared__ __align__(16) u16 kvb[48 * 72];    // kv bf16, padded stride
  __shared__ float a_s[8][40];
  __shared__ float o_s[2][64];
  __shared__ float qh_s[2][64];
  float* KVP = (float*)ybuf;  // stride 129 floats

  const int tid = threadIdx.x;
  const int lane = tid & 63;
  const int wv = tid >> 6;
  const int qd = lane >> 4;
  const int l16 = lane & 15;

  const int c2 = (tid & 31) * 2;
  const int lb = tid >> 5;
  const float pw_sc0 = rsqrtf(cbn_rv[c2] + EPS) * cbn_g[c2];
  const float pw_sc1 = rsqrtf(cbn_rv[c2 + 1] + EPS) * cbn_g[c2 + 1];
  const float pw_sh0 = cbn_b[c2] - cbn_rm[c2] * pw_sc0;
  const float pw_sh1 = cbn_b[c2 + 1] - cbn_rm[c2 + 1] * pw_sc1;
  const float pw_hpb0 = hp_b[c2], pw_hpb1 = hp_b[c2 + 1];
  const float pw_cvb0 = conv_b[c2], pw_cvb1 = conv_b[c2 + 1];
  const float lng = ln_g[lane], lnb = ln_b[lane];
  const float aob = attn_out_b[lane];
  const float kb0 = attn_in_b[64 + (wv * 2 + 0) * 16 + l16];
  const float kb1 = attn_in_b[64 + (wv * 2 + 1) * 16 + l16];

  for (int idx = tid; idx < 8 * 64; idx += 256)
    kvb[(40 + (idx >> 6)) * 72 + (idx & 63)] = 0;
  __syncthreads();

  unsigned xr[12];
  float mkr[3];
  {
    int np = blockIdx.x;
    int pb = np >> 1;
    const float* phn = (np & 1) ? hnB : hnA;
    const int* popp = (np & 1) ? oppB : oppA;
    const float* pmsk = (np & 1) ? mskB : mskA;
#pragma unroll
    for (int j = 0; j < 3; ++j) {
      int sidx = j * 256 + tid;
      int srow = sidx >> 4, scg = sidx & 15;
      if (srow < 40) {
        int mrow = pb * 40 + srow;
        mkr[j] = pmsk[mrow];
        const float* p = (scg < 4)
                             ? phn + (size_t)mrow * 32 + scg * 8
                             : temb + (size_t)popp[mrow] * 96 + (scg * 8 - 32);
        floatx4 f0 = *reinterpret_cast<const floatx4*>(p);
        floatx4 f1 = *reinterpret_cast<const floatx4*>(p + 4);
        xr[j * 4 + 0] = pack2bf(f0[0], f0[1]);
        xr[j * 4 + 1] = pack2bf(f0[2], f0[3]);
        xr[j * 4 + 2] = pack2bf(f1[0], f1[1]);
        xr[j * 4 + 3] = pack2bf(f1[2], f1[3]);
      } else {
        mkr[j] = 0.f;
        xr[j * 4 + 0] = xr[j * 4 + 1] = xr[j * 4 + 2] = xr[j * 4 + 3] = 0u;
      }
    }
  }

#pragma unroll 1
  for (int it = 0; it < 8; ++it) {
    int pair = blockIdx.x + it * 2048;
    int b = pair >> 1, s = pair & 1;

#pragma unroll
    for (int j = 0; j < 3; ++j) {
      int sidx = j * 256 + tid;
      bool keep = mkr[j] != 0.f;
      uintx4 v;
      v[0] = keep ? xr[j * 4 + 0] : 0u;
      v[1] = keep ? xr[j * 4 + 1] : 0u;
      v[2] = keep ? xr[j * 4 + 2] : 0u;
      v[3] = keep ? xr[j * 4 + 3] : 0u;
      *reinterpret_cast<uintx4*>(xb + (sidx >> 4) * 136 + (sidx & 15) * 8) = v;
    }
    float qreg = 0.f, qhreg = 0.f, m_l = 0.f;
    if (wv < 2) {
      int id = wv ? idB[b] : idA[b];
      qreg = Qg[id * 64 + lane];
      qhreg = QHg[id * 64 + lane];
      if (lane < 40) m_l = (s ? mskB : mskA)[b * 40 + lane];
    }
    __syncthreads();  // barrier1

    {
      short8 af[3][4];
#pragma unroll
      for (int mt = 0; mt < 3; ++mt)
#pragma unroll
        for (int ks = 0; ks < 4; ++ks)
          af[mt][ks] = *reinterpret_cast<const short8*>(
              xb + (mt * 16 + l16) * 136 + ks * 32 + (qd << 3));
      floatx4 acc[3][4] = {};
#pragma unroll
      for (int ntl = 0; ntl < 4; ++ntl) {
        short8 w[4];
#pragma unroll
        for (int ks = 0; ks < 4; ++ks)
          w[ks] = *reinterpret_cast<const short8*>(
              w1f + (((wv * 4 + ntl) * 4 + ks) * 64 + lane) * 8);
#pragma unroll
        for (int ks = 0; ks < 4; ++ks)
#pragma unroll
          for (int mt = 0; mt < 3; ++mt)
            acc[mt][ntl] = __builtin_amdgcn_mfma_f32_16x16x32_bf16(
                af[mt][ks], w[ks], acc[mt][ntl], 0, 0, 0);
      }
#pragma unroll
      for (int mt = 0; mt < 3; ++mt)
#pragma unroll
        for (int ntl = 0; ntl < 4; ++ntl)
#pragma unroll
          for (int r = 0; r < 4; ++r) {
            int row = mt * 16 + qd * 4 + r;
            int col = (wv * 4 + ntl) * 16 + l16;
            ybuf[row * 264 + col] = f2bf(acc[mt][ntl][r]);
          }
    }
    __syncthreads();  // barrier2

    float pf[3][8];
    float mknew[3];
    short8 bf2[2][2];
    {
      int np = (it < 7) ? pair + 2048 : pair;
      int pb = np >> 1;
      const float* phn = (np & 1) ? hnB : hnA;
      const int* popp = (np & 1) ? oppB : oppA;
      const float* pmsk = (np & 1) ? mskB : mskA;
#pragma unroll
      for (int j = 0; j < 3; ++j) {
        int sidx = j * 256 + tid;
        int srow = sidx >> 4, scg = sidx & 15;
        if (srow < 40) {
          int mrow = pb * 40 + srow;
          mknew[j] = pmsk[mrow];
          const float* p = (scg < 4)
                               ? phn + (size_t)mrow * 32 + scg * 8
                               : temb + (size_t)popp[mrow] * 96 + (scg * 8 - 32);
          *reinterpret_cast<floatx4*>(&pf[j][0]) = *reinterpret_cast<const floatx4*>(p);
          *reinterpret_cast<floatx4*>(&pf[j][4]) = *reinterpret_cast<const floatx4*>(p + 4);
        } else {
          mknew[j] = 0.f;
#pragma unroll
          for (int q = 0; q < 8; ++q) pf[j][q] = 0.f;
        }
      }
#pragma unroll
      for (int ntl = 0; ntl < 2; ++ntl)
#pragma unroll
        for (int ks = 0; ks < 2; ++ks)
          bf2[ntl][ks] = *reinterpret_cast<const short8*>(
              w2f + (((wv * 2 + ntl) * 2 + ks) * 64 + lane) * 8);
    }

#pragma unroll
    for (int t = 0; t < 5; ++t) {
      int l = lb + 8 * t;
      unsigned yhp = *reinterpret_cast<const unsigned*>(ybuf + l * 264 + c2);
      unsigned t0 = (l >= 1) ? *reinterpret_cast<const unsigned*>(ybuf + (l - 1) * 264 + 64 + c2) : 0u;
      unsigned t1 = *reinterpret_cast<const unsigned*>(ybuf + l * 264 + 128 + c2);
      unsigned t2 = *reinterpret_cast<const unsigned*>(ybuf + (l + 1) * 264 + 192 + c2);
      float res0 = silu_f(bf2f((u16)yhp) + pw_hpb0);
      float res1 = silu_f(bf2f((u16)(yhp >> 16)) + pw_hpb1);
      float c0 = bf2f((u16)t0) + bf2f((u16)t1) + bf2f((u16)t2) + pw_cvb0;
      float c1 = bf2f((u16)(t0 >> 16)) + bf2f((u16)(t1 >> 16)) + bf2f((u16)(t2 >> 16)) + pw_cvb1;
      float kv0 = silu_f(c0 * pw_sc0 + pw_sh0 + res0);
      float kv1 = silu_f(c1 * pw_sc1 + pw_sh1 + res1);
      *reinterpret_cast<unsigned*>(kvb + l * 72 + c2) = pack2bf(kv0, kv1);
    }
    __syncthreads();  // barrier3

    {
      floatx4 acc[3][2] = {};
#pragma unroll
      for (int mt = 0; mt < 3; ++mt) {
        short8 af[2];
#pragma unroll
        for (int ks = 0; ks < 2; ++ks)
          af[ks] = *reinterpret_cast<const short8*>(
              kvb + (mt * 16 + l16) * 72 + ks * 32 + (qd << 3));
#pragma unroll
        for (int ntl = 0; ntl < 2; ++ntl)
#pragma unroll
          for (int ks = 0; ks < 2; ++ks)
            acc[mt][ntl] = __builtin_amdgcn_mfma_f32_16x16x32_bf16(
                af[ks], bf2[ntl][ks], acc[mt][ntl], 0, 0, 0);
      }
#pragma unroll
      for (int mt = 0; mt < 3; ++mt)
#pragma unroll
        for (int ntl = 0; ntl < 2; ++ntl)
#pragma unroll
          for (int r = 0; r < 4; ++r) {
            int row = mt * 16 + qd * 4 + r;
            int col = (wv * 2 + ntl) * 16 + l16;
            KVP[row * 129 + col] = acc[mt][ntl][r] + (ntl ? kb1 : kb0);
          }
    }
    __syncthreads();  // barrier4

#pragma unroll
    for (int j = 0; j < 3; ++j) {
      xr[j * 4 + 0] = pack2bf(pf[j][0], pf[j][1]);
      xr[j * 4 + 1] = pack2bf(pf[j][2], pf[j][3]);
      xr[j * 4 + 2] = pack2bf(pf[j][4], pf[j][5]);
      xr[j * 4 + 3] = pack2bf(pf[j][6], pf[j][7]);
      mkr[j] = mknew[j];
    }

    if (wv < 2) {
      int qi = wv;
      qh_s[qi][lane] = qhreg;
      float a[4];
#pragma unroll
      for (int h = 0; h < 4; ++h) {
        float e = 0.f;
        if (lane < 40 && m_l > 0.f) {
          float acc = 0.f;
#pragma unroll
          for (int d = 0; d < 16; ++d)
            acc += qh_s[qi][h * 16 + d] * KVP[lane * 129 + h * 16 + d];
          e = __expf(acc * 0.25f);
        }
        float sm = wave_sum(e);
        a[h] = e / sm;
      }
#pragma unroll
      for (int h = 0; h < 4; ++h)
        if (lane < 40) a_s[qi * 4 + h][lane] = a[h];
      {
        int p = qi * 4 + (lane >> 4);
        float acc = 0.f;
#pragma unroll 4
        for (int l = 0; l < 40; ++l) acc += a_s[p][l] * KVP[l * 129 + 64 + lane];
        o_s[qi][lane] = acc;
      }
      float r = aob + qreg;
#pragma unroll 4
      for (int k = 0; k < 64; ++k) r += o_s[qi][k] * woT[k * 64 + lane];
      float mean = wave_sum(r) * (1.f / 64.f);
      float dv = r - mean;
      float var = wave_sum(dv * dv) * (1.f / 64.f);
      float outv = dv * rsqrtf(var + EPS) * lng + lnb;
      ATT[((qi * 2 + s) * 8192 + b) * 64 + lane] = outv;
    }
  }
}

// ---------------------------------------------------------------------------
// head_kernel: towers + residual MLP + heads, fp32, 8 batch rows per block.
// ---------------------------------------------------------------------------
__global__ __launch_bounds__(256) void head_kernel(
    const int* __restrict__ idA, const int* __restrict__ idB,
    const int* __restrict__ seedA, const int* __restrict__ seedB,
    const float* __restrict__ eloA, const float* __restrict__ eloB,
    const float* __restrict__ temb, const float* __restrict__ semb,
    const float* __restrict__ twT, const float* __restrict__ tw_b,
    const float* __restrict__ tbn_g, const float* __restrict__ tbn_b,
    const float* __restrict__ tbn_rm, const float* __restrict__ tbn_rv,
    const float* __restrict__ r1T, const float* __restrict__ r1_b,
    const float* __restrict__ r1bn_g, const float* __restrict__ r1bn_b,
    const float* __restrict__ r1bn_rm, const float* __restrict__ r1bn_rv,
    const float* __restrict__ r2T, const float* __restrict__ r2_b,
    const float* __restrict__ r2bn_g, const float* __restrict__ r2bn_b,
    const float* __restrict__ r2bn_rm, const float* __restrict__ r2bn_rv,
    const float* __restrict__ mu_w, const float* __restrict__ mu_b,
    const float* __restrict__ lv_w, const float* __restrict__ lv_b,
    const float* __restrict__ wl_w, const float* __restrict__ wl_b,
    const float* __restrict__ ATT, float* __restrict__ out) {
  __shared__ __align__(16) float tv[2][8][260];
  __shared__ __align__(16) float rr[2][8][128];
  __shared__ __align__(16) float xv[8][256];
  __shared__ __align__(16) float xw[8][256];
  const int tid = threadIdx.x;
  const int b0 = blockIdx.x * 8;

  for (int idx = tid; idx < 2 * 8 * 260; idx += 256) {
    int k = idx % 260;
    int bi = (idx / 260) & 7;
    int team = idx / (260 * 8);
    int b = b0 + bi;
    float v;
    if (k < 96) v = temb[(team ? idB[b] : idA[b]) * 96 + k];
    else if (k < 128) v = semb[(team ? seedB[b] : seedA[b]) * 32 + (k - 96)];
    else if (k == 128) v = ((team ? eloB[b] : eloA[b]) - 1500.f) * (1.f / 400.f);
    else if (k < 193) v = ATT[((team * 2 + team) * 8192 + b) * 64 + (k - 129)];
    else if (k < 257) v = ATT[((team * 2 + (1 - team)) * 8192 + b) * 64 + (k - 193)];
    else v = 0.f;
    tv[team][bi][k] = v;
  }
  __syncthreads();

  {
    int team = tid >> 7, mid = tid & 127;
    const floatx4* twv = reinterpret_cast<const floatx4*>(twT);
    float acc[8];
#pragma unroll
    for (int bi = 0; bi < 8; ++bi) acc[bi] = tw_b[mid];
#pragma unroll 2
    for (int k4 = 0; k4 < 65; ++k4) {
      floatx4 w4 = twv[k4 * 128 + mid];
      floatx4 x4[8];
#pragma unroll
      for (int bi = 0; bi < 8; ++bi)
        x4[bi] = *reinterpret_cast<const floatx4*>(&tv[team][bi][k4 * 4]);
#pragma unroll
      for (int bi = 0; bi < 8; ++bi)
        acc[bi] += x4[bi][0] * w4[0] + x4[bi][1] * w4[1] +
                   x4[bi][2] * w4[2] + x4[bi][3] * w4[3];
    }
    float sc = rsqrtf(tbn_rv[mid] + EPS) * tbn_g[mid];
    float sh = tbn_b[mid] - tbn_rm[mid] * sc;
#pragma unroll
    for (int bi = 0; bi < 8; ++bi) rr[team][bi][mid] = silu_f(acc[bi] * sc + sh);
  }
  __syncthreads();
  {
    int o = tid;
#pragma unroll
    for (int bi = 0; bi < 8; ++bi)
      xv[bi][o] = (o < 128) ? (rr[0][bi][o] - rr[1][bi][o])
                            : (rr[0][bi][o - 128] * rr[1][bi][o - 128]);
  }
  __syncthreads();
  {
    int o = tid;
    const floatx4* r1v = reinterpret_cast<const floatx4*>(r1T);
    float acc[8];
#pragma unroll
    for (int bi = 0; bi < 8; ++bi) acc[bi] = r1_b[o];
#pragma unroll 2
    for (int k4 = 0; k4 < 64; ++k4) {
      floatx4 w4 = r1v[k4 * 256 + o];
      floatx4 x4[8];
#pragma unroll
      for (int bi = 0; bi < 8; ++bi)
        x4[bi] = *reinterpret_cast<const floatx4*>(&xv[bi][k4 * 4]);
#pragma unroll
      for (int bi = 0; bi < 8; ++bi)
        acc[bi] += x4[bi][0] * w4[0] + x4[bi][1] * w4[1] +
                   x4[bi][2] * w4[2] + x4[bi][3] * w4[3];
    }
    float sc = rsqrtf(r1bn_rv[o] + EPS) * r1bn_g[o];
    float sh = r1bn_b[o] - r1bn_rm[o] * sc;
#pragma unroll
    for (int bi = 0; bi < 8; ++bi) xw[bi][o] = silu_f(acc[bi] * sc + sh) + xv[bi][o];
  }
  __syncthreads();
  {
    int o = tid;
    const floatx4* r2v = reinterpret_cast<const floatx4*>(r2T);
    float acc[8];
#pragma unroll
    for (int bi = 0; bi < 8; ++bi) acc[bi] = r2_b[o];
#pragma unroll 2
    for (int k4 = 0; k4 < 64; ++k4) {
      floatx4 w4 = r2v[k4 * 256 + o];
      floatx4 x4[8];
#pragma unroll
      for (int bi = 0; bi < 8; ++bi)
        x4[bi] = *reinterpret_cast<const floatx4*>(&xw[bi][k4 * 4]);
#pragma unroll
      for (int bi = 0; bi < 8; ++bi)
        acc[bi] += x4[bi][0] * w4[0] + x4[bi][1] * w4[1] +
                   x4[bi][2] * w4[2] + x4[bi][3] * w4[3];
    }
    float sc = rsqrtf(r2bn_rv[o] + EPS) * r2bn_g[o];
    float sh = r2bn_b[o] - r2bn_rm[o] * sc;
#pragma unroll
    for (int bi = 0; bi < 8; ++bi) xv[bi][o] = silu_f(acc[bi] * sc + sh) + xw[bi][o];
  }
  __syncthreads();
  if (tid < 136) {
    int bi = tid / 17, j = tid % 17;
    const float* wrow = (j < 8) ? (mu_w + j * 256) : (j < 16) ? (lv_w + (j - 8) * 256) : wl_w;
    const floatx4* wrow4 = reinterpret_cast<const floatx4*>(wrow);
    float acc = (j < 8) ? mu_b[j] : (j < 16) ? lv_b[j - 8] : wl_b[0];
    for (int k4 = 0; k4 < 64; ++k4) {
      floatx4 x4 = *reinterpret_cast<const floatx4*>(&xv[bi][k4 * 4]);
      floatx4 w4 = wrow4[k4];
      acc += x4[0] * w4[0] + x4[1] * w4[1] + x4[2] * w4[2] + x4[3] * w4[3];
    }
    int b = b0 + bi;
    if (j < 8) out[b * 8 + j] = acc;
    else if (j < 16) out[65536 + b * 8 + (j - 8)] = acc;
    else out[131072 + b] = acc;
  }
}

extern "C" void kernel_launch(void* const* d_in, const int* in_sizes, int n_in,
                              void* d_out, int out_size, void* d_ws, size_t ws_size,
                              hipStream_t stream) {
  const int* idA = (const int*)d_in[0];
  const int* idB = (const int*)d_in[1];
  const int* seedA = (const int*)d_in[2];
  const int* seedB = (const int*)d_in[3];
  const float* eloA = (const float*)d_in[4];
  const float* eloB = (const float*)d_in[5];
  const float* hnA = (const float*)d_in[6];
  const float* hnB = (const float*)d_in[7];
  const int* oppA = (const int*)d_in[8];
  const int* oppB = (const int*)d_in[9];
  const float* mskA = (const float*)d_in[10];
  const float* mskB = (const float*)d_in[11];
  const float* temb = (const float*)d_in[12];
  const float* semb = (const float*)d_in[13];
  const float* conv_w = (const float*)d_in[14];
  const float* conv_b = (const float*)d_in[15];
  const float* cbn_g = (const float*)d_in[16];
  const float* cbn_b = (const float*)d_in[17];
  const float* cbn_rm = (const float*)d_in[18];
  const float* cbn_rv = (const float*)d_in[19];
  const float* hp_w = (const float*)d_in[20];
  const float* hp_b = (const float*)d_in[21];
  const float* qp_w = (const float*)d_in[22];
  const float* qp_b = (const float*)d_in[23];
  const float* attn_in_w = (const float*)d_in[24];
  const float* attn_in_b = (const float*)d_in[25];
  const float* attn_out_w = (const float*)d_in[26];
  const float* attn_out_b = (const float*)d_in[27];
  const float* ln_g = (const float*)d_in[28];
  const float* ln_b = (const float*)d_in[29];
  const float* tw_w = (const float*)d_in[30];
  const float* tw_b = (const float*)d_in[31];
  const float* tbn_g = (const float*)d_in[32];
  const float* tbn_b = (const float*)d_in[33];
  const float* tbn_rm = (const float*)d_in[34];
  const float* tbn_rv = (const float*)d_in[35];
  const float* r1_w = (const float*)d_in[36];
  const float* r1_b = (const float*)d_in[37];
  const float* r1bn_g = (const float*)d_in[38];
  const float* r1bn_b = (const float*)d_in[39];
  const float* r1bn_rm = (const float*)d_in[40];
  const float* r1bn_rv = (const float*)d_in[41];
  const float* r2_w = (const float*)d_in[42];
  const float* r2_b = (const float*)d_in[43];
  const float* r2bn_g = (const float*)d_in[44];
  const float* r2bn_b = (const float*)d_in[45];
  const float* r2bn_rm = (const float*)d_in[46];
  const float* r2bn_rv = (const float*)d_in[47];
  const float* mu_w = (const float*)d_in[48];
  const float* mu_b = (const float*)d_in[49];
  const float* lv_w = (const float*)d_in[50];
  const float* lv_b = (const float*)d_in[51];
  const float* wl_w = (const float*)d_in[52];
  const float* wl_b = (const float*)d_in[53];

  char* ws = (char*)d_ws;
  u16* w1f = (u16*)(ws + 0);             //  65536 B
  u16* w2f = (u16*)(ws + 65536);         //  16384 B
  float* woT = (float*)(ws + 81920);     //  16384 B
  float* Qg = (float*)(ws + 98304);      // 102400 B
  float* QHg = (float*)(ws + 200704);    // 102400 B
  float* twT = (float*)(ws + 303104);    // 133120 B
  float* r1T = (float*)(ws + 436224);    // 262144 B
  float* r2T = (float*)(ws + 698368);    // 262144 B
  float* ATT = (float*)(ws + 960512);    // 8388608 B

  prep_kernel<<<256, 256, 0, stream>>>(hp_w, conv_w, attn_in_w, attn_out_w,
                                       tw_w, r1_w, r2_w,
                                       w1f, w2f, woT, twT, r1T, r2T);
  team_kernel<<<400, 64, 0, stream>>>(temb, qp_w, qp_b, attn_in_w, attn_in_b, Qg, QHg);
  attn_kernel<<<2048, 256, 0, stream>>>(idA, idB, hnA, hnB, oppA, oppB, mskA, mskB,
                                        temb, conv_b, cbn_g, cbn_b, cbn_rm, cbn_rv,
                                        hp_b, attn_in_b, attn_out_b, ln_g, ln_b,
                                        w1f, w2f, woT, Qg, QHg, ATT);
  head_kernel<<<1024, 256, 0, stream>>>(idA, idB, seedA, seedB, eloA, eloB, temb, semb,
                                        twT, tw_b, tbn_g, tbn_b, tbn_rm, tbn_rv,
                                        r1T, r1_b, r1bn_g, r1bn_b, r1bn_rm, r1bn_rv,
                                        r2T, r2_b, r2bn_g, r2bn_b, r2bn_rm, r2bn_rv,
                                        mu_w, mu_b, lv_w, lv_b, wl_w, wl_b,
                                        ATT, (float*)d_out);
}

// Round 10
// 583.921 us; speedup vs baseline: 1.8179x; 1.8179x over previous
//
#include <hip/hip_runtime.h>
#include <stdint.h>

#define EPS 1e-5f

typedef __attribute__((ext_vector_type(8))) short short8;
typedef __attribute__((ext_vector_type(4))) float floatx4;
typedef __attribute__((ext_vector_type(4))) unsigned uintx4;
typedef unsigned short u16;

__device__ __forceinline__ u16 f2bf(float f) {
  unsigned u = __builtin_bit_cast(unsigned, f);
  u += 0x7fffu + ((u >> 16) & 1u);
  return (u16)(u >> 16);
}
__device__ __forceinline__ float bf2f(u16 h) {
  return __builtin_bit_cast(float, (unsigned)h << 16);
}
__device__ __forceinline__ unsigned pack2bf(float a, float b) {
  return (unsigned)f2bf(a) | ((unsigned)f2bf(b) << 16);
}
__device__ __forceinline__ float silu_f(float x) { return x / (1.f + __expf(-x)); }
__device__ __forceinline__ float wave_sum(float x) {
  for (int off = 32; off > 0; off >>= 1) x += __shfl_xor(x, off);
  return x;
}

// ---------------------------------------------------------------------------
// prep: swizzle weights into MFMA fragment order + float4-packed k-major
// matrices for the head kernel.
// ---------------------------------------------------------------------------
__global__ void prep_kernel(const float* __restrict__ hp_w, const float* __restrict__ conv_w,
                            const float* __restrict__ attn_in_w,
                            const float* __restrict__ attn_out_w,
                            const float* __restrict__ tw_w, const float* __restrict__ r1_w,
                            const float* __restrict__ r2_w,
                            u16* __restrict__ w1f, u16* __restrict__ w2f,
                            float* __restrict__ woT,
                            float* __restrict__ twT, float* __restrict__ r1T,
                            float* __restrict__ r2T) {
  int t = blockIdx.x * 256 + threadIdx.x;  // 0..65535
  if (t < 32768) {
    int j = t & 7, lane = (t >> 3) & 63, ks = (t >> 9) & 3, nt = t >> 11;
    int k = ks * 32 + ((lane >> 4) << 3) + j;
    int n = nt * 16 + (lane & 15);
    float v = (n < 64) ? hp_w[n * 128 + k]
                       : conv_w[((n - 64) & 63) * 384 + k * 3 + ((n - 64) >> 6)];
    w1f[t] = f2bf(v);
  }
  if (t < 8192) {
    int j = t & 7, lane = (t >> 3) & 63, ks = (t >> 9) & 1, nt = t >> 10;
    int k = ks * 32 + ((lane >> 4) << 3) + j;
    int n = nt * 16 + (lane & 15);
    w2f[t] = f2bf(attn_in_w[(64 + n) * 64 + k]);
  }
  if (t < 4096) {
    int j = t & 63, k = t >> 6;
    woT[k * 64 + j] = attn_out_w[j * 64 + k];
  }
  if (t < 8320) {  // twT[k4 0..64][mid 0..127][4]; k=257..259 zero-padded
    int mid = t & 127, k4 = t >> 7;
#pragma unroll
    for (int i = 0; i < 4; ++i) {
      int k = k4 * 4 + i;
      twT[t * 4 + i] = (k < 257) ? tw_w[mid * 257 + k] : 0.f;
    }
  }
  if (t < 16384) {  // r1T/r2T[k4 0..63][o 0..255][4]
    int o = t & 255, k4 = t >> 8;
#pragma unroll
    for (int i = 0; i < 4; ++i) {
      r1T[t * 4 + i] = r1_w[o * 256 + k4 * 4 + i];
      r2T[t * 4 + i] = r2_w[o * 256 + k4 * 4 + i];
    }
  }
}

// ---------------------------------------------------------------------------
// team_kernel: per-team q = temb[t]@qp_w.T + qp_b ; qh = q@wq.T + bq
// ---------------------------------------------------------------------------
__global__ __launch_bounds__(64) void team_kernel(
    const float* __restrict__ temb, const float* __restrict__ qp_w,
    const float* __restrict__ qp_b, const float* __restrict__ attn_in_w,
    const float* __restrict__ attn_in_b,
    float* __restrict__ Qg, float* __restrict__ QHg) {
  __shared__ float e[96];
  __shared__ float qv[64];
  const int t = blockIdx.x;   // team id 0..399
  const int o = threadIdx.x;  // 0..63
  for (int i = o; i < 96; i += 64) e[i] = temb[t * 96 + i];
  __syncthreads();
  float acc = qp_b[o];
  for (int k = 0; k < 96; ++k) acc += e[k] * qp_w[o * 96 + k];
  qv[o] = acc;
  Qg[t * 64 + o] = acc;
  __syncthreads();
  float acc2 = attn_in_b[o];
  for (int k = 0; k < 64; ++k) acc2 += qv[k] * attn_in_w[o * 64 + k];
  QHg[t * 64 + o] = acc2;
}

// ---------------------------------------------------------------------------
// attn_kernel: round-6 structure under (256,2) (the no-spill config), with
// GEMM1 restructured to sequential ntl processing (#pragma unroll 1) to cut
// peak live registers from ~112 to ~76 in that phase. Goal: actual unified
// allocation <= 170/wave so HW schedules 3 blocks/CU WITHOUT a forced cap
// (r9 proved the (256,3) cap spills: VGPR 84, FETCH 750 MB).
// Diagnostic: FETCH must stay ~47.5 MB; occupancy 22 -> ~33 if it worked.
// ---------------------------------------------------------------------------
__global__ __launch_bounds__(256, 2) void attn_kernel(
    const int* __restrict__ idA, const int* __restrict__ idB,
    const float* __restrict__ hnA, const float* __restrict__ hnB,
    const int* __restrict__ oppA, const int* __restrict__ oppB,
    const float* __restrict__ mskA, const float* __restrict__ mskB,
    const float* __restrict__ temb, const float* __restrict__ conv_b,
    const float* __restrict__ cbn_g, const float* __restrict__ cbn_b,
    const float* __restrict__ cbn_rm, const float* __restrict__ cbn_rv,
    const float* __restrict__ hp_b,
    const float* __restrict__ attn_in_b, const float* __restrict__ attn_out_b,
    const float* __restrict__ ln_g, const float* __restrict__ ln_b,
    const u16* __restrict__ w1f, const u16* __restrict__ w2f,
    const float* __restrict__ woT,
    const float* __restrict__ Qg, const float* __restrict__ QHg,
    float* __restrict__ ATT) {
  __shared__ __align__(16) u16 xb[48 * 136];    // x tile bf16, padded stride
  __shared__ __align__(16) u16 ybuf[48 * 264];  // Y bf16; aliased as KVP fp32
  __shared__ __align__(16) u16 kvb[48 * 72];    // kv bf16, padded stride
  __shared__ float a_s[8][40];
  __shared__ float o_s[2][64];
  __shared__ float qh_s[2][64];
  float* KVP = (float*)ybuf;  // stride 129 floats

  const int tid = threadIdx.x;
  const int lane = tid & 63;
  const int wv = tid >> 6;
  const int qd = lane >> 4;
  const int l16 = lane & 15;

  const int c2 = (tid & 31) * 2;
  const int lb = tid >> 5;
  const float pw_sc0 = rsqrtf(cbn_rv[c2] + EPS) * cbn_g[c2];
  const float pw_sc1 = rsqrtf(cbn_rv[c2 + 1] + EPS) * cbn_g[c2 + 1];
  const float pw_sh0 = cbn_b[c2] - cbn_rm[c2] * pw_sc0;
  const float pw_sh1 = cbn_b[c2 + 1] - cbn_rm[c2 + 1] * pw_sc1;
  const float pw_hpb0 = hp_b[c2], pw_hpb1 = hp_b[c2 + 1];
  const float pw_cvb0 = conv_b[c2], pw_cvb1 = conv_b[c2 + 1];
  const float lng = ln_g[lane], lnb = ln_b[lane];
  const float aob = attn_out_b[lane];
  const float kb0 = attn_in_b[64 + (wv * 2 + 0) * 16 + l16];
  const float kb1 = attn_in_b[64 + (wv * 2 + 1) * 16 + l16];

  for (int idx = tid; idx < 8 * 64; idx += 256)
    kvb[(40 + (idx >> 6)) * 72 + (idx & 63)] = 0;
  __syncthreads();

  unsigned xr[12];
  float mkr[3];
  {
    int np = blockIdx.x;
    int pb = np >> 1;
    const float* phn = (np & 1) ? hnB : hnA;
    const int* popp = (np & 1) ? oppB : oppA;
    const float* pmsk = (np & 1) ? mskB : mskA;
#pragma unroll
    for (int j = 0; j < 3; ++j) {
      int sidx = j * 256 + tid;
      int srow = sidx >> 4, scg = sidx & 15;
      if (srow < 40) {
        int mrow = pb * 40 + srow;
        mkr[j] = pmsk[mrow];
        const float* p = (scg < 4)
                             ? phn + (size_t)mrow * 32 + scg * 8
                             : temb + (size_t)popp[mrow] * 96 + (scg * 8 - 32);
        floatx4 f0 = *reinterpret_cast<const floatx4*>(p);
        floatx4 f1 = *reinterpret_cast<const floatx4*>(p + 4);
        xr[j * 4 + 0] = pack2bf(f0[0], f0[1]);
        xr[j * 4 + 1] = pack2bf(f0[2], f0[3]);
        xr[j * 4 + 2] = pack2bf(f1[0], f1[1]);
        xr[j * 4 + 3] = pack2bf(f1[2], f1[3]);
      } else {
        mkr[j] = 0.f;
        xr[j * 4 + 0] = xr[j * 4 + 1] = xr[j * 4 + 2] = xr[j * 4 + 3] = 0u;
      }
    }
  }

#pragma unroll 1
  for (int it = 0; it < 8; ++it) {
    int pair = blockIdx.x + it * 2048;
    int b = pair >> 1, s = pair & 1;

#pragma unroll
    for (int j = 0; j < 3; ++j) {
      int sidx = j * 256 + tid;
      bool keep = mkr[j] != 0.f;
      uintx4 v;
      v[0] = keep ? xr[j * 4 + 0] : 0u;
      v[1] = keep ? xr[j * 4 + 1] : 0u;
      v[2] = keep ? xr[j * 4 + 2] : 0u;
      v[3] = keep ? xr[j * 4 + 3] : 0u;
      *reinterpret_cast<uintx4*>(xb + (sidx >> 4) * 136 + (sidx & 15) * 8) = v;
    }
    float qreg = 0.f, qhreg = 0.f, m_l = 0.f;
    if (wv < 2) {
      int id = wv ? idB[b] : idA[b];
      qreg = Qg[id * 64 + lane];
      qhreg = QHg[id * 64 + lane];
      if (lane < 40) m_l = (s ? mskB : mskA)[b * 40 + lane];
    }
    __syncthreads();  // barrier1

    // ---- Phase A: GEMM1, sequential per-ntl to cap live registers ----
    {
      short8 af[3][4];
#pragma unroll
      for (int mt = 0; mt < 3; ++mt)
#pragma unroll
        for (int ks = 0; ks < 4; ++ks)
          af[mt][ks] = *reinterpret_cast<const short8*>(
              xb + (mt * 16 + l16) * 136 + ks * 32 + (qd << 3));
#pragma unroll 1
      for (int ntl = 0; ntl < 4; ++ntl) {
        short8 w[4];
#pragma unroll
        for (int ks = 0; ks < 4; ++ks)
          w[ks] = *reinterpret_cast<const short8*>(
              w1f + (((wv * 4 + ntl) * 4 + ks) * 64 + lane) * 8);
        floatx4 acc[3] = {};
#pragma unroll
        for (int ks = 0; ks < 4; ++ks)
#pragma unroll
          for (int mt = 0; mt < 3; ++mt)
            acc[mt] = __builtin_amdgcn_mfma_f32_16x16x32_bf16(
                af[mt][ks], w[ks], acc[mt], 0, 0, 0);
        int col = (wv * 4 + ntl) * 16 + l16;
#pragma unroll
        for (int mt = 0; mt < 3; ++mt)
#pragma unroll
          for (int r = 0; r < 4; ++r)
            ybuf[(mt * 16 + qd * 4 + r) * 264 + col] = f2bf(acc[mt][r]);
      }
    }
    __syncthreads();  // barrier2

    float pf[3][8];
    float mknew[3];
    short8 bf2[2][2];
    {
      int np = (it < 7) ? pair + 2048 : pair;
      int pb = np >> 1;
      const float* phn = (np & 1) ? hnB : hnA;
      const int* popp = (np & 1) ? oppB : oppA;
      const float* pmsk = (np & 1) ? mskB : mskA;
#pragma unroll
      for (int j = 0; j < 3; ++j) {
        int sidx = j * 256 + tid;
        int srow = sidx >> 4, scg = sidx & 15;
        if (srow < 40) {
          int mrow = pb * 40 + srow;
          mknew[j] = pmsk[mrow];
          const float* p = (scg < 4)
                               ? phn + (size_t)mrow * 32 + scg * 8
                               : temb + (size_t)popp[mrow] * 96 + (scg * 8 - 32);
          *reinterpret_cast<floatx4*>(&pf[j][0]) = *reinterpret_cast<const floatx4*>(p);
          *reinterpret_cast<floatx4*>(&pf[j][4]) = *reinterpret_cast<const floatx4*>(p + 4);
        } else {
          mknew[j] = 0.f;
#pragma unroll
          for (int q = 0; q < 8; ++q) pf[j][q] = 0.f;
        }
      }
#pragma unroll
      for (int ntl = 0; ntl < 2; ++ntl)
#pragma unroll
        for (int ks = 0; ks < 2; ++ks)
          bf2[ntl][ks] = *reinterpret_cast<const short8*>(
              w2f + (((wv * 2 + ntl) * 2 + ks) * 64 + lane) * 8);
    }

#pragma unroll
    for (int t = 0; t < 5; ++t) {
      int l = lb + 8 * t;
      unsigned yhp = *reinterpret_cast<const unsigned*>(ybuf + l * 264 + c2);
      unsigned t0 = (l >= 1) ? *reinterpret_cast<const unsigned*>(ybuf + (l - 1) * 264 + 64 + c2) : 0u;
      unsigned t1 = *reinterpret_cast<const unsigned*>(ybuf + l * 264 + 128 + c2);
      unsigned t2 = *reinterpret_cast<const unsigned*>(ybuf + (l + 1) * 264 + 192 + c2);
      float res0 = silu_f(bf2f((u16)yhp) + pw_hpb0);
      float res1 = silu_f(bf2f((u16)(yhp >> 16)) + pw_hpb1);
      float c0 = bf2f((u16)t0) + bf2f((u16)t1) + bf2f((u16)t2) + pw_cvb0;
      float c1 = bf2f((u16)(t0 >> 16)) + bf2f((u16)(t1 >> 16)) + bf2f((u16)(t2 >> 16)) + pw_cvb1;
      float kv0 = silu_f(c0 * pw_sc0 + pw_sh0 + res0);
      float kv1 = silu_f(c1 * pw_sc1 + pw_sh1 + res1);
      *reinterpret_cast<unsigned*>(kvb + l * 72 + c2) = pack2bf(kv0, kv1);
    }
    __syncthreads();  // barrier3

    {
      floatx4 acc[3][2] = {};
#pragma unroll
      for (int mt = 0; mt < 3; ++mt) {
        short8 af[2];
#pragma unroll
        for (int ks = 0; ks < 2; ++ks)
          af[ks] = *reinterpret_cast<const short8*>(
              kvb + (mt * 16 + l16) * 72 + ks * 32 + (qd << 3));
#pragma unroll
        for (int ntl = 0; ntl < 2; ++ntl)
#pragma unroll
          for (int ks = 0; ks < 2; ++ks)
            acc[mt][ntl] = __builtin_amdgcn_mfma_f32_16x16x32_bf16(
                af[ks], bf2[ntl][ks], acc[mt][ntl], 0, 0, 0);
      }
#pragma unroll
      for (int mt = 0; mt < 3; ++mt)
#pragma unroll
        for (int ntl = 0; ntl < 2; ++ntl)
#pragma unroll
          for (int r = 0; r < 4; ++r) {
            int row = mt * 16 + qd * 4 + r;
            int col = (wv * 2 + ntl) * 16 + l16;
            KVP[row * 129 + col] = acc[mt][ntl][r] + (ntl ? kb1 : kb0);
          }
    }
    __syncthreads();  // barrier4

#pragma unroll
    for (int j = 0; j < 3; ++j) {
      xr[j * 4 + 0] = pack2bf(pf[j][0], pf[j][1]);
      xr[j * 4 + 1] = pack2bf(pf[j][2], pf[j][3]);
      xr[j * 4 + 2] = pack2bf(pf[j][4], pf[j][5]);
      xr[j * 4 + 3] = pack2bf(pf[j][6], pf[j][7]);
      mkr[j] = mknew[j];
    }

    if (wv < 2) {
      int qi = wv;
      qh_s[qi][lane] = qhreg;
      float a[4];
#pragma unroll
      for (int h = 0; h < 4; ++h) {
        float e = 0.f;
        if (lane < 40 && m_l > 0.f) {
          float acc = 0.f;
#pragma unroll
          for (int d = 0; d < 16; ++d)
            acc += qh_s[qi][h * 16 + d] * KVP[lane * 129 + h * 16 + d];
          e = __expf(acc * 0.25f);
        }
        float sm = wave_sum(e);
        a[h] = e / sm;
      }
#pragma unroll
      for (int h = 0; h < 4; ++h)
        if (lane < 40) a_s[qi * 4 + h][lane] = a[h];
      {
        int p = qi * 4 + (lane >> 4);
        float acc = 0.f;
#pragma unroll 4
        for (int l = 0; l < 40; ++l) acc += a_s[p][l] * KVP[l * 129 + 64 + lane];
        o_s[qi][lane] = acc;
      }
      float r = aob + qreg;
#pragma unroll 4
      for (int k = 0; k < 64; ++k) r += o_s[qi][k] * woT[k * 64 + lane];
      float mean = wave_sum(r) * (1.f / 64.f);
      float dv = r - mean;
      float var = wave_sum(dv * dv) * (1.f / 64.f);
      float outv = dv * rsqrtf(var + EPS) * lng + lnb;
      ATT[((qi * 2 + s) * 8192 + b) * 64 + lane] = outv;
    }
  }
}

// ---------------------------------------------------------------------------
// head_kernel: towers + residual MLP + heads, fp32, 8 batch rows per block.
// ---------------------------------------------------------------------------
__global__ __launch_bounds__(256) void head_kernel(
    const int* __restrict__ idA, const int* __restrict__ idB,
    const int* __restrict__ seedA, const int* __restrict__ seedB,
    const float* __restrict__ eloA, const float* __restrict__ eloB,
    const float* __restrict__ temb, const float* __restrict__ semb,
    const float* __restrict__ twT, const float* __restrict__ tw_b,
    const float* __restrict__ tbn_g, const float* __restrict__ tbn_b,
    const float* __restrict__ tbn_rm, const float* __restrict__ tbn_rv,
    const float* __restrict__ r1T, const float* __restrict__ r1_b,
    const float* __restrict__ r1bn_g, const float* __restrict__ r1bn_b,
    const float* __restrict__ r1bn_rm, const float* __restrict__ r1bn_rv,
    const float* __restrict__ r2T, const float* __restrict__ r2_b,
    const float* __restrict__ r2bn_g, const float* __restrict__ r2bn_b,
    const float* __restrict__ r2bn_rm, const float* __restrict__ r2bn_rv,
    const float* __restrict__ mu_w, const float* __restrict__ mu_b,
    const float* __restrict__ lv_w, const float* __restrict__ lv_b,
    const float* __restrict__ wl_w, const float* __restrict__ wl_b,
    const float* __restrict__ ATT, float* __restrict__ out) {
  __shared__ __align__(16) float tv[2][8][260];
  __shared__ __align__(16) float rr[2][8][128];
  __shared__ __align__(16) float xv[8][256];
  __shared__ __align__(16) float xw[8][256];
  const int tid = threadIdx.x;
  const int b0 = blockIdx.x * 8;

  for (int idx = tid; idx < 2 * 8 * 260; idx += 256) {
    int k = idx % 260;
    int bi = (idx / 260) & 7;
    int team = idx / (260 * 8);
    int b = b0 + bi;
    float v;
    if (k < 96) v = temb[(team ? idB[b] : idA[b]) * 96 + k];
    else if (k < 128) v = semb[(team ? seedB[b] : seedA[b]) * 32 + (k - 96)];
    else if (k == 128) v = ((team ? eloB[b] : eloA[b]) - 1500.f) * (1.f / 400.f);
    else if (k < 193) v = ATT[((team * 2 + team) * 8192 + b) * 64 + (k - 129)];
    else if (k < 257) v = ATT[((team * 2 + (1 - team)) * 8192 + b) * 64 + (k - 193)];
    else v = 0.f;
    tv[team][bi][k] = v;
  }
  __syncthreads();

  {
    int team = tid >> 7, mid = tid & 127;
    const floatx4* twv = reinterpret_cast<const floatx4*>(twT);
    float acc[8];
#pragma unroll
    for (int bi = 0; bi < 8; ++bi) acc[bi] = tw_b[mid];
#pragma unroll 2
    for (int k4 = 0; k4 < 65; ++k4) {
      floatx4 w4 = twv[k4 * 128 + mid];
      floatx4 x4[8];
#pragma unroll
      for (int bi = 0; bi < 8; ++bi)
        x4[bi] = *reinterpret_cast<const floatx4*>(&tv[team][bi][k4 * 4]);
#pragma unroll
      for (int bi = 0; bi < 8; ++bi)
        acc[bi] += x4[bi][0] * w4[0] + x4[bi][1] * w4[1] +
                   x4[bi][2] * w4[2] + x4[bi][3] * w4[3];
    }
    float sc = rsqrtf(tbn_rv[mid] + EPS) * tbn_g[mid];
    float sh = tbn_b[mid] - tbn_rm[mid] * sc;
#pragma unroll
    for (int bi = 0; bi < 8; ++bi) rr[team][bi][mid] = silu_f(acc[bi] * sc + sh);
  }
  __syncthreads();
  {
    int o = tid;
#pragma unroll
    for (int bi = 0; bi < 8; ++bi)
      xv[bi][o] = (o < 128) ? (rr[0][bi][o] - rr[1][bi][o])
                            : (rr[0][bi][o - 128] * rr[1][bi][o - 128]);
  }
  __syncthreads();
  {
    int o = tid;
    const floatx4* r1v = reinterpret_cast<const floatx4*>(r1T);
    float acc[8];
#pragma unroll
    for (int bi = 0; bi < 8; ++bi) acc[bi] = r1_b[o];
#pragma unroll 2
    for (int k4 = 0; k4 < 64; ++k4) {
      floatx4 w4 = r1v[k4 * 256 + o];
      floatx4 x4[8];
#pragma unroll
      for (int bi = 0; bi < 8; ++bi)
        x4[bi] = *reinterpret_cast<const floatx4*>(&xv[bi][k4 * 4]);
#pragma unroll
      for (int bi = 0; bi < 8; ++bi)
        acc[bi] += x4[bi][0] * w4[0] + x4[bi][1] * w4[1] +
                   x4[bi][2] * w4[2] + x4[bi][3] * w4[3];
    }
    float sc = rsqrtf(r1bn_rv[o] + EPS) * r1bn_g[o];
    float sh = r1bn_b[o] - r1bn_rm[o] * sc;
#pragma unroll
    for (int bi = 0; bi < 8; ++bi) xw[bi][o] = silu_f(acc[bi] * sc + sh) + xv[bi][o];
  }
  __syncthreads();
  {
    int o = tid;
    const floatx4* r2v = reinterpret_cast<const floatx4*>(r2T);
    float acc[8];
#pragma unroll
    for (int bi = 0; bi < 8; ++bi) acc[bi] = r2_b[o];
#pragma unroll 2
    for (int k4 = 0; k4 < 64; ++k4) {
      floatx4 w4 = r2v[k4 * 256 + o];
      floatx4 x4[8];
#pragma unroll
      for (int bi = 0; bi < 8; ++bi)
        x4[bi] = *reinterpret_cast<const floatx4*>(&xw[bi][k4 * 4]);
#pragma unroll
      for (int bi = 0; bi < 8; ++bi)
        acc[bi] += x4[bi][0] * w4[0] + x4[bi][1] * w4[1] +
                   x4[bi][2] * w4[2] + x4[bi][3] * w4[3];
    }
    float sc = rsqrtf(r2bn_rv[o] + EPS) * r2bn_g[o];
    float sh = r2bn_b[o] - r2bn_rm[o] * sc;
#pragma unroll
    for (int bi = 0; bi < 8; ++bi) xv[bi][o] = silu_f(acc[bi] * sc + sh) + xw[bi][o];
  }
  __syncthreads();
  if (tid < 136) {
    int bi = tid / 17, j = tid % 17;
    const float* wrow = (j < 8) ? (mu_w + j * 256) : (j < 16) ? (lv_w + (j - 8) * 256) : wl_w;
    const floatx4* wrow4 = reinterpret_cast<const floatx4*>(wrow);
    float acc = (j < 8) ? mu_b[j] : (j < 16) ? lv_b[j - 8] : wl_b[0];
    for (int k4 = 0; k4 < 64; ++k4) {
      floatx4 x4 = *reinterpret_cast<const floatx4*>(&xv[bi][k4 * 4]);
      floatx4 w4 = wrow4[k4];
      acc += x4[0] * w4[0] + x4[1] * w4[1] + x4[2] * w4[2] + x4[3] * w4[3];
    }
    int b = b0 + bi;
    if (j < 8) out[b * 8 + j] = acc;
    else if (j < 16) out[65536 + b * 8 + (j - 8)] = acc;
    else out[131072 + b] = acc;
  }
}

extern "C" void kernel_launch(void* const* d_in, const int* in_sizes, int n_in,
                              void* d_out, int out_size, void* d_ws, size_t ws_size,
                              hipStream_t stream) {
  const int* idA = (const int*)d_in[0];
  const int* idB = (const int*)d_in[1];
  const int* seedA = (const int*)d_in[2];
  const int* seedB = (const int*)d_in[3];
  const float* eloA = (const float*)d_in[4];
  const float* eloB = (const float*)d_in[5];
  const float* hnA = (const float*)d_in[6];
  const float* hnB = (const float*)d_in[7];
  const int* oppA = (const int*)d_in[8];
  const int* oppB = (const int*)d_in[9];
  const float* mskA = (const float*)d_in[10];
  const float* mskB = (const float*)d_in[11];
  const float* temb = (const float*)d_in[12];
  const float* semb = (const float*)d_in[13];
  const float* conv_w = (const float*)d_in[14];
  const float* conv_b = (const float*)d_in[15];
  const float* cbn_g = (const float*)d_in[16];
  const float* cbn_b = (const float*)d_in[17];
  const float* cbn_rm = (const float*)d_in[18];
  const float* cbn_rv = (const float*)d_in[19];
  const float* hp_w = (const float*)d_in[20];
  const float* hp_b = (const float*)d_in[21];
  const float* qp_w = (const float*)d_in[22];
  const float* qp_b = (const float*)d_in[23];
  const float* attn_in_w = (const float*)d_in[24];
  const float* attn_in_b = (const float*)d_in[25];
  const float* attn_out_w = (const float*)d_in[26];
  const float* attn_out_b = (const float*)d_in[27];
  const float* ln_g = (const float*)d_in[28];
  const float* ln_b = (const float*)d_in[29];
  const float* tw_w = (const float*)d_in[30];
  const float* tw_b = (const float*)d_in[31];
  const float* tbn_g = (const float*)d_in[32];
  const float* tbn_b = (const float*)d_in[33];
  const float* tbn_rm = (const float*)d_in[34];
  const float* tbn_rv = (const float*)d_in[35];
  const float* r1_w = (const float*)d_in[36];
  const float* r1_b = (const float*)d_in[37];
  const float* r1bn_g = (const float*)d_in[38];
  const float* r1bn_b = (const float*)d_in[39];
  const float* r1bn_rm = (const float*)d_in[40];
  const float* r1bn_rv = (const float*)d_in[41];
  const float* r2_w = (const float*)d_in[42];
  const float* r2_b = (const float*)d_in[43];
  const float* r2bn_g = (const float*)d_in[44];
  const float* r2bn_b = (const float*)d_in[45];
  const float* r2bn_rm = (const float*)d_in[46];
  const float* r2bn_rv = (const float*)d_in[47];
  const float* mu_w = (const float*)d_in[48];
  const float* mu_b = (const float*)d_in[49];
  const float* lv_w = (const float*)d_in[50];
  const float* lv_b = (const float*)d_in[51];
  const float* wl_w = (const float*)d_in[52];
  const float* wl_b = (const float*)d_in[53];

  char* ws = (char*)d_ws;
  u16* w1f = (u16*)(ws + 0);             //  65536 B
  u16* w2f = (u16*)(ws + 65536);         //  16384 B
  float* woT = (float*)(ws + 81920);     //  16384 B
  float* Qg = (float*)(ws + 98304);      // 102400 B
  float* QHg = (float*)(ws + 200704);    // 102400 B
  float* twT = (float*)(ws + 303104);    // 133120 B
  float* r1T = (float*)(ws + 436224);    // 262144 B
  float* r2T = (float*)(ws + 698368);    // 262144 B
  float* ATT = (float*)(ws + 960512);    // 8388608 B

  prep_kernel<<<256, 256, 0, stream>>>(hp_w, conv_w, attn_in_w, attn_out_w,
                                       tw_w, r1_w, r2_w,
                                       w1f, w2f, woT, twT, r1T, r2T);
  team_kernel<<<400, 64, 0, stream>>>(temb, qp_w, qp_b, attn_in_w, attn_in_b, Qg, QHg);
  attn_kernel<<<2048, 256, 0, stream>>>(idA, idB, hnA, hnB, oppA, oppB, mskA, mskB,
                                        temb, conv_b, cbn_g, cbn_b, cbn_rm, cbn_rv,
                                        hp_b, attn_in_b, attn_out_b, ln_g, ln_b,
                                        w1f, w2f, woT, Qg, QHg, ATT);
  head_kernel<<<1024, 256, 0, stream>>>(idA, idB, seedA, seedB, eloA, eloB, temb, semb,
                                        twT, tw_b, tbn_g, tbn_b, tbn_rm, tbn_rv,
                                        r1T, r1_b, r1bn_g, r1bn_b, r1bn_rm, r1bn_rv,
                                        r2T, r2_b, r2bn_g, r2bn_b, r2bn_rm, r2bn_rv,
                                        mu_w, mu_b, lv_w, lv_b, wl_w, wl_b,
                                        ATT, (float*)d_out);
}